// Round 3
// baseline (1719.104 us; speedup 1.0000x reference)
//
#include <hip/hip_runtime.h>
#include <math.h>

#define N_B 16
#define T_LEN 4096

// ---- workspace layout (float offsets) ----
static const size_t OFF_A    = 0;            // 16*128*4096 (enc h1 / dec h2)
static const size_t OFF_B    = 8388608;      // 16*256*4096 (enc h2 / dec h1)
static const size_t OFF_Z    = 25165824;     // 16*64*4096  (z, aliased by quantized)
static const size_t OFF_WT1  = 29360128;     // 30720
static const size_t OFF_WT2  = 29390848;     // 98304
static const size_t OFF_WT3  = 29489152;     // 16384
static const size_t OFF_WD1  = 29505536;     // 49152
static const size_t OFF_WD2  = 29554688;     // 98304
static const size_t OFF_WD3  = 29652992;     // 30720
static const size_t OFF_C2   = 29683712;     // 512 floats (f32-rounded |c|^2)
static const size_t OFF_ST   = 29684736;     // 256 double2
static const size_t OFF_LOSS = 29685760;     // 1 double

// ---- weight transpose helper: w[CO][CI][KS] -> wT[KS][CI][CO] ----
template<int C_OUT, int C_IN, int KS>
__device__ inline void tw(const float* __restrict__ w, float* __restrict__ wT, int e) {
    int co  = e / (C_IN * KS);
    int rem = e - co * (C_IN * KS);
    int ci  = rem / KS;
    int k   = rem - ci * KS;
    wT[(k * C_IN + ci) * C_OUT + co] = w[e];
}

// ---- prep: transpose all 6 weights, codebook row norms (f64->f32), zero loss ----
__global__ __launch_bounds__(256) void prep_k(
        const float* __restrict__ w1, const float* __restrict__ w2,
        const float* __restrict__ w3, const float* __restrict__ wd1,
        const float* __restrict__ wd2, const float* __restrict__ wd3,
        const float* __restrict__ cb, float* wsf) {
    int e = blockIdx.x * 256 + threadIdx.x;
    if (e < 30720)        tw<128,  80, 3>(w1,  wsf + OFF_WT1, e);
    else if (e < 129024)  tw<256, 128, 3>(w2,  wsf + OFF_WT2, e - 30720);
    else if (e < 145408)  tw< 64, 256, 1>(w3,  wsf + OFF_WT3, e - 129024);
    else if (e < 194560)  tw<256,  64, 3>(wd1, wsf + OFF_WD1, e - 145408);
    else if (e < 292864)  tw<128, 256, 3>(wd2, wsf + OFF_WD2, e - 194560);
    else if (e < 323584)  tw< 80, 128, 3>(wd3, wsf + OFF_WD3, e - 292864);
    else if (e < 324096) {
        int c = e - 323584;
        const float* p = cb + (size_t)c * 64;
        double s = 0.0;
        for (int d = 0; d < 64; ++d) { double v = p[d]; s += v * v; }
        wsf[OFF_C2 + c] = (float)s;   // f32-rounded |c|^2, as the f32 ref has
    } else if (e == 324096) {
        *(double*)(wsf + OFF_LOSS) = 0.0;
    }
}

// ---- generic conv1d (+ optional fused BN+ReLU on the INPUT, applied in f64) ----
template<int C_IN, int C_OUT, int KS, bool BN_IN, typename ACC>
__global__ __launch_bounds__(256) void conv_k(
        const float* __restrict__ x, const float* __restrict__ wT,
        const float* __restrict__ bias, const double2* __restrict__ stats,
        float* __restrict__ out) {
    constexpr int T_TILE = 128;
    constexpr int CI_CH  = 32;
    constexpr int XCOLS  = T_TILE + KS - 1;
    constexpr int XROW   = (KS == 3) ? 132 : 128;

    __shared__ __align__(16) float xs[CI_CH * XROW];
    __shared__ __align__(16) float ws[KS * CI_CH * 64];

    const int tid = threadIdx.x;
    const int tx  = tid & 15;
    const int ty  = tid >> 4;
    const int n    = blockIdx.x >> 5;
    const int t0   = (blockIdx.x & 31) * T_TILE;
    const int co0  = blockIdx.y * 64;

    ACC acc[4][8];
#pragma unroll
    for (int i = 0; i < 4; ++i)
#pragma unroll
        for (int j = 0; j < 8; ++j) acc[i][j] = (ACC)0;

    for (int ci0 = 0; ci0 < C_IN; ci0 += CI_CH) {
        __syncthreads();
        for (int e = tid; e < CI_CH * XCOLS; e += 256) {
            int ci = e / XCOLS;
            int tt = e - ci * XCOLS;
            int cig = ci0 + ci;
            int gt  = t0 + tt - (KS / 2);
            float v = 0.f;
            if (cig < C_IN && gt >= 0 && gt < T_LEN) {
                v = x[((size_t)(n * C_IN + cig)) * T_LEN + gt];
                if (BN_IN) {
                    double2 s = stats[cig];
                    double vv = fma((double)v, s.x, s.y);
                    v = (float)fmax(vv, 0.0);
                }
            }
            xs[ci * XROW + tt] = v;
        }
        for (int e = tid; e < KS * CI_CH * 64; e += 256) {
            int co = e & 63;
            int r  = e >> 6;
            int ci = r & (CI_CH - 1);
            int k  = r >> 5;
            int cig = ci0 + ci, cog = co0 + co;
            float v = 0.f;
            if (cig < C_IN && cog < C_OUT)
                v = wT[((size_t)(k * C_IN + cig)) * C_OUT + cog];
            ws[(k * CI_CH + ci) * 64 + co] = v;
        }
        __syncthreads();

        for (int ci = 0; ci < CI_CH; ++ci) {
            ACC xv[10];
            {
                const float* xr = &xs[ci * XROW + tx * 8];
                float4 a0 = *(const float4*)&xr[0];
                float4 a1 = *(const float4*)&xr[4];
                xv[0] = (ACC)a0.x; xv[1] = (ACC)a0.y; xv[2] = (ACC)a0.z; xv[3] = (ACC)a0.w;
                xv[4] = (ACC)a1.x; xv[5] = (ACC)a1.y; xv[6] = (ACC)a1.z; xv[7] = (ACC)a1.w;
                if (KS == 3) {
                    float2 a2 = *(const float2*)&xr[8];
                    xv[8] = (ACC)a2.x; xv[9] = (ACC)a2.y;
                } else { xv[8] = (ACC)0; xv[9] = (ACC)0; }
            }
            ACC wa[KS][4];
#pragma unroll
            for (int k = 0; k < KS; ++k) {
                float4 wv = *(const float4*)&ws[(k * CI_CH + ci) * 64 + ty * 4];
                wa[k][0] = (ACC)wv.x; wa[k][1] = (ACC)wv.y;
                wa[k][2] = (ACC)wv.z; wa[k][3] = (ACC)wv.w;
            }
#pragma unroll
            for (int k = 0; k < KS; ++k)
#pragma unroll
                for (int i = 0; i < 4; ++i)
#pragma unroll
                    for (int j = 0; j < 8; ++j)
                        acc[i][j] = fma(wa[k][i], xv[j + k], acc[i][j]);
        }
    }

    const size_t tb = (size_t)t0 + (size_t)tx * 8;
#pragma unroll
    for (int i = 0; i < 4; ++i) {
        int co = co0 + ty * 4 + i;
        if (co < C_OUT) {
            ACC bv = (ACC)bias[co];
            float* o = out + ((size_t)(n * C_OUT + co)) * T_LEN + tb;
            float r[8];
#pragma unroll
            for (int j = 0; j < 8; ++j) r[j] = (float)(acc[i][j] + bv);
            *(float4*)&o[0] = make_float4(r[0], r[1], r[2], r[3]);
            *(float4*)&o[4] = make_float4(r[4], r[5], r[6], r[7]);
        }
    }
}

// ---- training-mode BN stats (f64) ----
__global__ __launch_bounds__(256) void stats_k(
        const float* __restrict__ y, int C, const float* __restrict__ g,
        const float* __restrict__ b, double2* __restrict__ stats) {
    int c = blockIdx.x, tid = threadIdx.x;
    double s1 = 0.0, s2 = 0.0;
    for (int n = 0; n < N_B; ++n) {
        const float* p = y + ((size_t)(n * C + c)) * T_LEN;
        for (int t = tid; t < T_LEN; t += 256) {
            double v = p[t];
            s1 += v; s2 += v * v;
        }
    }
    __shared__ double r1[256], r2[256];
    r1[tid] = s1; r2[tid] = s2;
    __syncthreads();
    for (int s = 128; s > 0; s >>= 1) {
        if (tid < s) { r1[tid] += r1[tid + s]; r2[tid] += r2[tid + s]; }
        __syncthreads();
    }
    if (tid == 0) {
        double m   = r1[0] / 65536.0;
        double var = r2[0] / 65536.0 - m * m;
        double sc  = (double)g[c] / sqrt(var + 1e-5);
        stats[c] = make_double2(sc, (double)b[c] - m * sc);
    }
}

// ---- VQ: replicate the reference's f32 d2 formula exactly ----
// d2 = f32( f32(|z|^2_f32 + |c|^2_f32) - 2*f32(z.c) ), argmin w/ low-idx ties.
// Dot products in f64, rounded to f32 once (within ~0.002 ulp of ref's BLAS f32).
__global__ __launch_bounds__(256) void vq_k(
        const float* z, const float* __restrict__ cb,
        const float* __restrict__ c2, float* q,
        float* __restrict__ idx_out, double* __restrict__ loss) {
    __shared__ __align__(16) float zs[64 * 68];
    __shared__ __align__(16) float cs[64 * 68];
    __shared__ float  szf[64];
    __shared__ float  redS[64 * 16];
    __shared__ int    redI[64 * 16];
    __shared__ int    idxs[64];
    __shared__ double dred[256];

    const int tid = threadIdx.x;
    const int tx  = tid & 15, ty = tid >> 4;
    const int n   = blockIdx.x >> 6;
    const int t0  = (blockIdx.x & 63) * 64;

    for (int e = tid; e < 4096; e += 256) {
        int t = e & 63, d = e >> 6;
        zs[t * 68 + d] = z[((size_t)(n * 64 + d)) * T_LEN + t0 + t];
    }
    __syncthreads();
    if (tid < 64) {                       // |z|^2 per row, f64 -> f32 once
        double s = 0.0;
        const float* zr = &zs[tid * 68];
        for (int d = 0; d < 64; ++d) { double v = zr[d]; s += v * v; }
        szf[tid] = (float)s;
    }

    float best[4];
    int bidx[4];
#pragma unroll
    for (int i = 0; i < 4; ++i) { best[i] = 3.0e38f; bidx[i] = 1 << 30; }

    for (int ch = 0; ch < 8; ++ch) {
        __syncthreads();
        for (int e = tid; e < 4096; e += 256) {
            int d = e & 63, c = e >> 6;
            cs[c * 68 + d] = cb[((size_t)(ch * 64 + c)) * 64 + d];
        }
        __syncthreads();

        double acc[4][4];
#pragma unroll
        for (int i = 0; i < 4; ++i)
#pragma unroll
            for (int j = 0; j < 4; ++j) acc[i][j] = 0.0;

        for (int d = 0; d < 64; d += 4) {
            float4 zv[4], cv[4];
#pragma unroll
            for (int i = 0; i < 4; ++i)
                zv[i] = *(const float4*)&zs[(tx + 16 * i) * 68 + d];
#pragma unroll
            for (int j = 0; j < 4; ++j)
                cv[j] = *(const float4*)&cs[(ty + 16 * j) * 68 + d];
#pragma unroll
            for (int i = 0; i < 4; ++i)
#pragma unroll
                for (int j = 0; j < 4; ++j) {
                    acc[i][j] = fma((double)zv[i].x, (double)cv[j].x, acc[i][j]);
                    acc[i][j] = fma((double)zv[i].y, (double)cv[j].y, acc[i][j]);
                    acc[i][j] = fma((double)zv[i].z, (double)cv[j].z, acc[i][j]);
                    acc[i][j] = fma((double)zv[i].w, (double)cv[j].w, acc[i][j]);
                }
        }
#pragma unroll
        for (int j = 0; j < 4; ++j) {
            int cg = ch * 64 + ty + 16 * j;
            float cc = c2[cg];
#pragma unroll
            for (int i = 0; i < 4; ++i) {
                float m32 = (float)acc[i][j];          // f32(z.c), once
                float A   = szf[tx + 16 * i] + cc;     // f32(|z|^2 + |c|^2)
                float s   = A - 2.0f * m32;            // f32 final, the ref grid
                if (s < best[i] || (s == best[i] && cg < bidx[i])) {
                    best[i] = s; bidx[i] = cg;
                }
            }
        }
    }
#pragma unroll
    for (int i = 0; i < 4; ++i) {
        redS[(tx + 16 * i) * 16 + ty] = best[i];
        redI[(tx + 16 * i) * 16 + ty] = bidx[i];
    }
    __syncthreads();

    if (tid < 64) {
        int t = tid;
        float bs = 3.0e38f; int bi = 1 << 30;
        for (int y2 = 0; y2 < 16; ++y2) {
            float v = redS[t * 16 + y2];
            int vi  = redI[t * 16 + y2];
            if (v < bs || (v == bs && vi < bi)) { bs = v; bi = vi; }
        }
        idxs[t] = bi;
        idx_out[(size_t)n * T_LEN + t0 + t] = (float)bi;
    }
    __syncthreads();

    {
        int g = tid >> 6, t = tid & 63;
        int bi = idxs[t];
        double ls = 0.0;
        for (int dd = 0; dd < 16; ++dd) {
            int d = g * 16 + dd;
            float qv = cb[(size_t)bi * 64 + d];
            float zv = zs[t * 68 + d];
            double df = (double)qv - (double)zv;
            ls += df * df;
            q[((size_t)(n * 64 + d)) * T_LEN + t0 + t] = qv;
        }
        dred[tid] = ls;
    }
    __syncthreads();
    for (int s = 128; s > 0; s >>= 1) {
        if (tid < s) dred[tid] += dred[tid + s];
        __syncthreads();
    }
    if (tid == 0) atomicAdd(loss, dred[0]);
}

__global__ void fin_k(const double* __restrict__ loss, float* __restrict__ out) {
    if (threadIdx.x == 0 && blockIdx.x == 0)
        out[0] = (float)(1.25 * (*loss) / 4194304.0);
}

extern "C" void kernel_launch(void* const* d_in, const int* in_sizes, int n_in,
                              void* d_out, int out_size, void* d_ws, size_t ws_size,
                              hipStream_t stream) {
    const float* x      = (const float*)d_in[0];
    const float* enc_w1 = (const float*)d_in[1];
    const float* enc_b1 = (const float*)d_in[2];
    const float* bn1_g  = (const float*)d_in[3];
    const float* bn1_b  = (const float*)d_in[4];
    const float* enc_w2 = (const float*)d_in[5];
    const float* enc_b2 = (const float*)d_in[6];
    const float* bn2_g  = (const float*)d_in[7];
    const float* bn2_b  = (const float*)d_in[8];
    const float* enc_w3 = (const float*)d_in[9];
    const float* enc_b3 = (const float*)d_in[10];
    const float* cb     = (const float*)d_in[11];
    const float* dec_w1 = (const float*)d_in[12];
    const float* dec_b1 = (const float*)d_in[13];
    const float* dbn1_g = (const float*)d_in[14];
    const float* dbn1_b = (const float*)d_in[15];
    const float* dec_w2 = (const float*)d_in[16];
    const float* dec_b2 = (const float*)d_in[17];
    const float* dbn2_g = (const float*)d_in[18];
    const float* dbn2_b = (const float*)d_in[19];
    const float* dec_w3 = (const float*)d_in[20];
    const float* dec_b3 = (const float*)d_in[21];

    float* wsf   = (float*)d_ws;
    float* outf  = (float*)d_out;
    float* A     = wsf + OFF_A;
    float* Bb    = wsf + OFF_B;
    float* Z     = wsf + OFF_Z;
    double2* st  = (double2*)(wsf + OFF_ST);
    double* lossp = (double*)(wsf + OFF_LOSS);

    prep_k<<<1268, 256, 0, stream>>>(enc_w1, enc_w2, enc_w3,
                                     dec_w1, dec_w2, dec_w3, cb, wsf);

    // encoder (f64 accumulation)
    conv_k<80, 128, 3, false, double><<<dim3(512, 2), 256, 0, stream>>>(
        x, wsf + OFF_WT1, enc_b1, nullptr, A);
    stats_k<<<128, 256, 0, stream>>>(A, 128, bn1_g, bn1_b, st);
    conv_k<128, 256, 3, true, double><<<dim3(512, 4), 256, 0, stream>>>(
        A, wsf + OFF_WT2, enc_b2, st, Bb);
    stats_k<<<256, 256, 0, stream>>>(Bb, 256, bn2_g, bn2_b, st);
    conv_k<256, 64, 1, true, double><<<dim3(512, 1), 256, 0, stream>>>(
        Bb, wsf + OFF_WT3, enc_b3, st, Z);

    // vector quantizer — f32-formula scores, exact ref grid
    vq_k<<<1024, 256, 0, stream>>>(Z, cb, wsf + OFF_C2, Z,
                                   outf + 5242881, lossp);
    fin_k<<<1, 64, 0, stream>>>(lossp, outf + 5242880);

    // decoder (f32)
    conv_k<64, 256, 3, false, float><<<dim3(512, 4), 256, 0, stream>>>(
        Z, wsf + OFF_WD1, dec_b1, nullptr, Bb);
    stats_k<<<256, 256, 0, stream>>>(Bb, 256, dbn1_g, dbn1_b, st);
    conv_k<256, 128, 3, true, float><<<dim3(512, 2), 256, 0, stream>>>(
        Bb, wsf + OFF_WD2, dec_b2, st, A);
    stats_k<<<128, 256, 0, stream>>>(A, 128, dbn2_g, dbn2_b, st);
    conv_k<128, 80, 3, true, float><<<dim3(512, 2), 256, 0, stream>>>(
        A, wsf + OFF_WD3, dec_b3, st, outf);
}

// Round 4
// 1298.500 us; speedup vs baseline: 1.3239x; 1.3239x over previous
//
#include <hip/hip_runtime.h>
#include <math.h>

#define N_B 16
#define T_LEN 4096

// ---- workspace layout (float offsets) ----
static const size_t OFF_A    = 0;            // 16*128*4096 (enc h1 / dec h2)
static const size_t OFF_B    = 8388608;      // 16*256*4096 (enc h2 / dec h1)
static const size_t OFF_Z    = 25165824;     // 16*64*4096  (z, aliased by quantized)
static const size_t OFF_WT1  = 29360128;     // 30720
static const size_t OFF_WT2  = 29390848;     // 98304
static const size_t OFF_WT3  = 29489152;     // 16384
static const size_t OFF_WD1  = 29505536;     // 49152
static const size_t OFF_WD2  = 29554688;     // 98304
static const size_t OFF_WD3  = 29652992;     // 30720
static const size_t OFF_C2   = 29683712;     // 512 floats (f32-rounded |c|^2)
static const size_t OFF_ST   = 29684736;     // 256 double2
static const size_t OFF_LOSS = 29685760;     // 1 double

// ---- weight transpose helper: w[CO][CI][KS] -> wT[KS][CI][CO] ----
template<int C_OUT, int C_IN, int KS>
__device__ inline void tw(const float* __restrict__ w, float* __restrict__ wT, int e) {
    int co  = e / (C_IN * KS);
    int rem = e - co * (C_IN * KS);
    int ci  = rem / KS;
    int k   = rem - ci * KS;
    wT[(k * C_IN + ci) * C_OUT + co] = w[e];
}

// ---- prep: transpose all 6 weights, codebook row norms (f64->f32), zero loss ----
__global__ __launch_bounds__(256) void prep_k(
        const float* __restrict__ w1, const float* __restrict__ w2,
        const float* __restrict__ w3, const float* __restrict__ wd1,
        const float* __restrict__ wd2, const float* __restrict__ wd3,
        const float* __restrict__ cb, float* wsf) {
    int e = blockIdx.x * 256 + threadIdx.x;
    if (e < 30720)        tw<128,  80, 3>(w1,  wsf + OFF_WT1, e);
    else if (e < 129024)  tw<256, 128, 3>(w2,  wsf + OFF_WT2, e - 30720);
    else if (e < 145408)  tw< 64, 256, 1>(w3,  wsf + OFF_WT3, e - 129024);
    else if (e < 194560)  tw<256,  64, 3>(wd1, wsf + OFF_WD1, e - 145408);
    else if (e < 292864)  tw<128, 256, 3>(wd2, wsf + OFF_WD2, e - 194560);
    else if (e < 323584)  tw< 80, 128, 3>(wd3, wsf + OFF_WD3, e - 292864);
    else if (e < 324096) {
        int c = e - 323584;
        const float* p = cb + (size_t)c * 64;
        double s = 0.0;
        for (int d = 0; d < 64; ++d) { double v = p[d]; s += v * v; }
        wsf[OFF_C2 + c] = (float)s;   // f32-rounded |c|^2, as the f32 ref has
    } else if (e == 324096) {
        *(double*)(wsf + OFF_LOSS) = 0.0;
    }
}

// ---- generic conv1d (+ optional fused BN+ReLU on the INPUT, applied in f64) ----
// tile: 128 t x 64 c_out per block, 256 threads, 8t x 4co regs per thread.
// CI_CH=16 for KS=3 keeps LDS at ~20.7KB -> 7 blocks/CU (was 3).
template<int C_IN, int C_OUT, int KS, bool BN_IN, typename ACC>
__global__ __launch_bounds__(256) void conv_k(
        const float* __restrict__ x, const float* __restrict__ wT,
        const float* __restrict__ bias, const double2* __restrict__ stats,
        float* __restrict__ out) {
    constexpr int T_TILE = 128;
    constexpr int CI_CH  = (KS == 3) ? 16 : 32;
    constexpr int CI_SH  = (KS == 3) ? 4 : 5;        // log2(CI_CH)
    constexpr int XCOLS  = T_TILE + KS - 1;
    constexpr int XROW   = (KS == 3) ? 132 : 128;

    __shared__ __align__(16) float xs[CI_CH * XROW];
    __shared__ __align__(16) float ws[KS * CI_CH * 64];

    const int tid = threadIdx.x;
    const int tx  = tid & 15;
    const int ty  = tid >> 4;
    const int n    = blockIdx.x >> 5;
    const int t0   = (blockIdx.x & 31) * T_TILE;
    const int co0  = blockIdx.y * 64;

    ACC acc[4][8];
#pragma unroll
    for (int i = 0; i < 4; ++i)
#pragma unroll
        for (int j = 0; j < 8; ++j) acc[i][j] = (ACC)0;

    for (int ci0 = 0; ci0 < C_IN; ci0 += CI_CH) {
        __syncthreads();
        for (int e = tid; e < CI_CH * XCOLS; e += 256) {
            int ci = e / XCOLS;
            int tt = e - ci * XCOLS;
            int cig = ci0 + ci;
            int gt  = t0 + tt - (KS / 2);
            float v = 0.f;
            if (cig < C_IN && gt >= 0 && gt < T_LEN) {
                v = x[((size_t)(n * C_IN + cig)) * T_LEN + gt];
                if (BN_IN) {
                    double2 s = stats[cig];
                    double vv = fma((double)v, s.x, s.y);
                    v = (float)fmax(vv, 0.0);
                }
            }
            xs[ci * XROW + tt] = v;
        }
        for (int e = tid; e < KS * CI_CH * 64; e += 256) {
            int co = e & 63;
            int r  = e >> 6;
            int ci = r & (CI_CH - 1);
            int k  = r >> CI_SH;
            int cig = ci0 + ci, cog = co0 + co;
            float v = 0.f;
            if (cig < C_IN && cog < C_OUT)
                v = wT[((size_t)(k * C_IN + cig)) * C_OUT + cog];
            ws[(k * CI_CH + ci) * 64 + co] = v;
        }
        __syncthreads();

        for (int ci = 0; ci < CI_CH; ++ci) {
            ACC xv[10];
            {
                const float* xr = &xs[ci * XROW + tx * 8];
                float4 a0 = *(const float4*)&xr[0];
                float4 a1 = *(const float4*)&xr[4];
                xv[0] = (ACC)a0.x; xv[1] = (ACC)a0.y; xv[2] = (ACC)a0.z; xv[3] = (ACC)a0.w;
                xv[4] = (ACC)a1.x; xv[5] = (ACC)a1.y; xv[6] = (ACC)a1.z; xv[7] = (ACC)a1.w;
                if (KS == 3) {
                    float2 a2 = *(const float2*)&xr[8];
                    xv[8] = (ACC)a2.x; xv[9] = (ACC)a2.y;
                } else { xv[8] = (ACC)0; xv[9] = (ACC)0; }
            }
            ACC wa[KS][4];
#pragma unroll
            for (int k = 0; k < KS; ++k) {
                float4 wv = *(const float4*)&ws[(k * CI_CH + ci) * 64 + ty * 4];
                wa[k][0] = (ACC)wv.x; wa[k][1] = (ACC)wv.y;
                wa[k][2] = (ACC)wv.z; wa[k][3] = (ACC)wv.w;
            }
#pragma unroll
            for (int k = 0; k < KS; ++k)
#pragma unroll
                for (int i = 0; i < 4; ++i)
#pragma unroll
                    for (int j = 0; j < 8; ++j)
                        acc[i][j] = fma(wa[k][i], xv[j + k], acc[i][j]);
        }
    }

    const size_t tb = (size_t)t0 + (size_t)tx * 8;
#pragma unroll
    for (int i = 0; i < 4; ++i) {
        int co = co0 + ty * 4 + i;
        if (co < C_OUT) {
            ACC bv = (ACC)bias[co];
            float* o = out + ((size_t)(n * C_OUT + co)) * T_LEN + tb;
            float r[8];
#pragma unroll
            for (int j = 0; j < 8; ++j) r[j] = (float)(acc[i][j] + bv);
            *(float4*)&o[0] = make_float4(r[0], r[1], r[2], r[3]);
            *(float4*)&o[4] = make_float4(r[4], r[5], r[6], r[7]);
        }
    }
}

// ---- BN stats stage 1: one block per (channel, batch) row -> partial sums ----
__global__ __launch_bounds__(256) void stats1_k(
        const float* __restrict__ y, int C, double2* __restrict__ part) {
    int c = blockIdx.x % C, n = blockIdx.x / C;
    int tid = threadIdx.x;
    const float* p = y + ((size_t)(n * C + c)) * T_LEN;
    double s1 = 0.0, s2 = 0.0;
    for (int t = tid; t < T_LEN; t += 256) {
        double v = p[t];
        s1 += v; s2 += v * v;
    }
    __shared__ double r1[256], r2[256];
    r1[tid] = s1; r2[tid] = s2;
    __syncthreads();
    for (int s = 128; s > 0; s >>= 1) {
        if (tid < s) { r1[tid] += r1[tid + s]; r2[tid] += r2[tid + s]; }
        __syncthreads();
    }
    if (tid == 0) part[(size_t)c * N_B + n] = make_double2(r1[0], r2[0]);
}

// ---- BN stats stage 2: deterministic combine -> (scale, shift) per channel ----
__global__ __launch_bounds__(256) void stats2_k(
        const double2* __restrict__ part, int C, const float* __restrict__ g,
        const float* __restrict__ b, double2* __restrict__ stats) {
    int c = blockIdx.x * 256 + threadIdx.x;
    if (c >= C) return;
    double s1 = 0.0, s2 = 0.0;
    for (int n = 0; n < N_B; ++n) {
        double2 v = part[(size_t)c * N_B + n];
        s1 += v.x; s2 += v.y;
    }
    double m   = s1 / 65536.0;
    double var = s2 / 65536.0 - m * m;
    double sc  = (double)g[c] / sqrt(var + 1e-5);
    stats[c] = make_double2(sc, (double)b[c] - m * sc);
}

// ---- VQ: replicate the reference's f32 d2 formula exactly ----
// d2 = f32( f32(|z|^2_f32 + |c|^2_f32) - 2*f32(z.c) ), argmin w/ low-idx ties.
__global__ __launch_bounds__(256) void vq_k(
        const float* z, const float* __restrict__ cb,
        const float* __restrict__ c2, float* q,
        float* __restrict__ idx_out, double* __restrict__ loss) {
    __shared__ __align__(16) float zs[64 * 68];
    __shared__ __align__(16) float cs[64 * 68];
    __shared__ float  szf[64];
    __shared__ float  redS[64 * 16];
    __shared__ int    redI[64 * 16];
    __shared__ int    idxs[64];
    __shared__ double dred[256];

    const int tid = threadIdx.x;
    const int tx  = tid & 15, ty = tid >> 4;
    const int n   = blockIdx.x >> 6;
    const int t0  = (blockIdx.x & 63) * 64;

    for (int e = tid; e < 4096; e += 256) {
        int t = e & 63, d = e >> 6;
        zs[t * 68 + d] = z[((size_t)(n * 64 + d)) * T_LEN + t0 + t];
    }
    __syncthreads();
    if (tid < 64) {                       // |z|^2 per row, f64 -> f32 once
        double s = 0.0;
        const float* zr = &zs[tid * 68];
        for (int d = 0; d < 64; ++d) { double v = zr[d]; s += v * v; }
        szf[tid] = (float)s;
    }

    float best[4];
    int bidx[4];
#pragma unroll
    for (int i = 0; i < 4; ++i) { best[i] = 3.0e38f; bidx[i] = 1 << 30; }

    for (int ch = 0; ch < 8; ++ch) {
        __syncthreads();
        for (int e = tid; e < 4096; e += 256) {
            int d = e & 63, c = e >> 6;
            cs[c * 68 + d] = cb[((size_t)(ch * 64 + c)) * 64 + d];
        }
        __syncthreads();

        double acc[4][4];
#pragma unroll
        for (int i = 0; i < 4; ++i)
#pragma unroll
            for (int j = 0; j < 4; ++j) acc[i][j] = 0.0;

        for (int d = 0; d < 64; d += 4) {
            float4 zv[4], cv[4];
#pragma unroll
            for (int i = 0; i < 4; ++i)
                zv[i] = *(const float4*)&zs[(tx + 16 * i) * 68 + d];
#pragma unroll
            for (int j = 0; j < 4; ++j)
                cv[j] = *(const float4*)&cs[(ty + 16 * j) * 68 + d];
#pragma unroll
            for (int i = 0; i < 4; ++i)
#pragma unroll
                for (int j = 0; j < 4; ++j) {
                    acc[i][j] = fma((double)zv[i].x, (double)cv[j].x, acc[i][j]);
                    acc[i][j] = fma((double)zv[i].y, (double)cv[j].y, acc[i][j]);
                    acc[i][j] = fma((double)zv[i].z, (double)cv[j].z, acc[i][j]);
                    acc[i][j] = fma((double)zv[i].w, (double)cv[j].w, acc[i][j]);
                }
        }
#pragma unroll
        for (int j = 0; j < 4; ++j) {
            int cg = ch * 64 + ty + 16 * j;
            float cc = c2[cg];
#pragma unroll
            for (int i = 0; i < 4; ++i) {
                float m32 = (float)acc[i][j];          // f32(z.c), once
                float A   = szf[tx + 16 * i] + cc;     // f32(|z|^2 + |c|^2)
                float s   = A - 2.0f * m32;            // f32 final, the ref grid
                if (s < best[i] || (s == best[i] && cg < bidx[i])) {
                    best[i] = s; bidx[i] = cg;
                }
            }
        }
    }
#pragma unroll
    for (int i = 0; i < 4; ++i) {
        redS[(tx + 16 * i) * 16 + ty] = best[i];
        redI[(tx + 16 * i) * 16 + ty] = bidx[i];
    }
    __syncthreads();

    if (tid < 64) {
        int t = tid;
        float bs = 3.0e38f; int bi = 1 << 30;
        for (int y2 = 0; y2 < 16; ++y2) {
            float v = redS[t * 16 + y2];
            int vi  = redI[t * 16 + y2];
            if (v < bs || (v == bs && vi < bi)) { bs = v; bi = vi; }
        }
        idxs[t] = bi;
        idx_out[(size_t)n * T_LEN + t0 + t] = (float)bi;
    }
    __syncthreads();

    {
        int g = tid >> 6, t = tid & 63;
        int bi = idxs[t];
        double ls = 0.0;
        for (int dd = 0; dd < 16; ++dd) {
            int d = g * 16 + dd;
            float qv = cb[(size_t)bi * 64 + d];
            float zv = zs[t * 68 + d];
            double df = (double)qv - (double)zv;
            ls += df * df;
            q[((size_t)(n * 64 + d)) * T_LEN + t0 + t] = qv;
        }
        dred[tid] = ls;
    }
    __syncthreads();
    for (int s = 128; s > 0; s >>= 1) {
        if (tid < s) dred[tid] += dred[tid + s];
        __syncthreads();
    }
    if (tid == 0) atomicAdd(loss, dred[0]);
}

__global__ void fin_k(const double* __restrict__ loss, float* __restrict__ out) {
    if (threadIdx.x == 0 && blockIdx.x == 0)
        out[0] = (float)(1.25 * (*loss) / 4194304.0);
}

extern "C" void kernel_launch(void* const* d_in, const int* in_sizes, int n_in,
                              void* d_out, int out_size, void* d_ws, size_t ws_size,
                              hipStream_t stream) {
    const float* x      = (const float*)d_in[0];
    const float* enc_w1 = (const float*)d_in[1];
    const float* enc_b1 = (const float*)d_in[2];
    const float* bn1_g  = (const float*)d_in[3];
    const float* bn1_b  = (const float*)d_in[4];
    const float* enc_w2 = (const float*)d_in[5];
    const float* enc_b2 = (const float*)d_in[6];
    const float* bn2_g  = (const float*)d_in[7];
    const float* bn2_b  = (const float*)d_in[8];
    const float* enc_w3 = (const float*)d_in[9];
    const float* enc_b3 = (const float*)d_in[10];
    const float* cb     = (const float*)d_in[11];
    const float* dec_w1 = (const float*)d_in[12];
    const float* dec_b1 = (const float*)d_in[13];
    const float* dbn1_g = (const float*)d_in[14];
    const float* dbn1_b = (const float*)d_in[15];
    const float* dec_w2 = (const float*)d_in[16];
    const float* dec_b2 = (const float*)d_in[17];
    const float* dbn2_g = (const float*)d_in[18];
    const float* dbn2_b = (const float*)d_in[19];
    const float* dec_w3 = (const float*)d_in[20];
    const float* dec_b3 = (const float*)d_in[21];

    float* wsf   = (float*)d_ws;
    float* outf  = (float*)d_out;
    float* A     = wsf + OFF_A;
    float* Bb    = wsf + OFF_B;
    float* Z     = wsf + OFF_Z;
    double2* st  = (double2*)(wsf + OFF_ST);
    double* lossp = (double*)(wsf + OFF_LOSS);
    // stats partials live in whichever ping-pong buffer is dead at that point
    double2* partA = (double2*)A;
    double2* partB = (double2*)Bb;

    prep_k<<<1268, 256, 0, stream>>>(enc_w1, enc_w2, enc_w3,
                                     dec_w1, dec_w2, dec_w3, cb, wsf);

    // encoder (f64 accumulation; f32 storage per layer — matches np ref contract)
    conv_k<80, 128, 3, false, double><<<dim3(512, 2), 256, 0, stream>>>(
        x, wsf + OFF_WT1, enc_b1, nullptr, A);
    stats1_k<<<128 * N_B, 256, 0, stream>>>(A, 128, partB);
    stats2_k<<<1, 256, 0, stream>>>(partB, 128, bn1_g, bn1_b, st);
    conv_k<128, 256, 3, true, double><<<dim3(512, 4), 256, 0, stream>>>(
        A, wsf + OFF_WT2, enc_b2, st, Bb);
    stats1_k<<<256 * N_B, 256, 0, stream>>>(Bb, 256, partA);
    stats2_k<<<1, 256, 0, stream>>>(partA, 256, bn2_g, bn2_b, st);
    conv_k<256, 64, 1, true, double><<<dim3(512, 1), 256, 0, stream>>>(
        Bb, wsf + OFF_WT3, enc_b3, st, Z);

    // vector quantizer — f32-formula scores, exact ref grid
    vq_k<<<1024, 256, 0, stream>>>(Z, cb, wsf + OFF_C2, Z,
                                   outf + 5242881, lossp);
    fin_k<<<1, 64, 0, stream>>>(lossp, outf + 5242880);

    // decoder (f32)
    conv_k<64, 256, 3, false, float><<<dim3(512, 4), 256, 0, stream>>>(
        Z, wsf + OFF_WD1, dec_b1, nullptr, Bb);
    stats1_k<<<256 * N_B, 256, 0, stream>>>(Bb, 256, partA);
    stats2_k<<<1, 256, 0, stream>>>(partA, 256, dbn1_g, dbn1_b, st);
    conv_k<256, 128, 3, true, float><<<dim3(512, 2), 256, 0, stream>>>(
        Bb, wsf + OFF_WD2, dec_b2, st, A);
    stats1_k<<<128 * N_B, 256, 0, stream>>>(A, 128, partB);
    stats2_k<<<1, 256, 0, stream>>>(partB, 128, dbn2_g, dbn2_b, st);
    conv_k<128, 80, 3, true, float><<<dim3(512, 2), 256, 0, stream>>>(
        A, wsf + OFF_WD3, dec_b3, st, outf);
}